// Round 1
// baseline (92.715 us; speedup 1.0000x reference)
//
#include <hip/hip_runtime.h>
#include <math.h>

// ---- DCT basis with the 0.25 global scale folded symmetrically (BB = 0.5*B1)
// so  F[i,j,u*8+v] = BB[i][u]*BB[j][v]  works for BOTH forward and inverse.
#define H1 0.49039264020161522f
#define H2 0.46193976625564338f
#define H3 0.41573480615127262f
#define H4 0.35355339059327376f
#define H5 0.27778511650980111f
#define H6 0.19134171618254489f
#define H7 0.09754516100806413f

__device__ __constant__ float cBB[64] = {
  H4,  H1,  H2,  H3,  H4,  H5,  H6,  H7,
  H4,  H3,  H6, -H7, -H4, -H1, -H2, -H5,
  H4,  H5, -H6, -H1, -H4,  H7,  H2,  H3,
  H4,  H7, -H2, -H5,  H4,  H3, -H6, -H1,
  H4, -H7, -H2,  H5,  H4, -H3, -H6,  H1,
  H4, -H5, -H6,  H1, -H4, -H7,  H2, -H3,
  H4, -H3,  H6,  H7, -H4,  H1, -H2,  H5,
  H4, -H1,  H2, -H3,  H4, -H5,  H6, -H7,
};

__device__ __constant__ float cQ[64] = {
  16.f/255.f, 11.f/255.f, 10.f/255.f, 16.f/255.f, 24.f/255.f, 40.f/255.f, 51.f/255.f, 61.f/255.f,
  12.f/255.f, 12.f/255.f, 14.f/255.f, 19.f/255.f, 26.f/255.f, 58.f/255.f, 60.f/255.f, 55.f/255.f,
  14.f/255.f, 13.f/255.f, 16.f/255.f, 24.f/255.f, 40.f/255.f, 57.f/255.f, 69.f/255.f, 56.f/255.f,
  14.f/255.f, 17.f/255.f, 22.f/255.f, 29.f/255.f, 51.f/255.f, 87.f/255.f, 80.f/255.f, 62.f/255.f,
  18.f/255.f, 22.f/255.f, 37.f/255.f, 56.f/255.f, 68.f/255.f, 109.f/255.f, 103.f/255.f, 77.f/255.f,
  24.f/255.f, 35.f/255.f, 55.f/255.f, 64.f/255.f, 81.f/255.f, 104.f/255.f, 113.f/255.f, 92.f/255.f,
  49.f/255.f, 64.f/255.f, 78.f/255.f, 87.f/255.f, 103.f/255.f, 121.f/255.f, 120.f/255.f, 101.f/255.f,
  72.f/255.f, 92.f/255.f, 95.f/255.f, 98.f/255.f, 112.f/255.f, 100.f/255.f, 103.f/255.f, 99.f/255.f,
};

__device__ __forceinline__ float clampf(float x, float lo, float hi) {
    return fminf(fmaxf(x, lo), hi);
}
__device__ __forceinline__ float sgnf(float x) {
    return (x > 0.f) ? 1.f : ((x < 0.f) ? -1.f : 0.f);
}

__global__ __launch_bounds__(256)
void smooth_jpeg_kernel(const float* __restrict__ s, float* __restrict__ out)
{
    const int t    = threadIdx.x;
    const int py   = t >> 4, px = t & 15;
    const int tile = blockIdx.x;          // 4 * 32 * 32 tiles
    const int b    = tile >> 10;
    const int ti   = tile & 1023;
    const int tr   = ti >> 5;
    const int tc   = ti & 31;
    const int gy   = tr * 16 + py;
    const int gx   = tc * 16 + px;

    __shared__ float BBl[64];
    __shared__ float Ql[64];
    __shared__ float ly[256];     // luma tile (16x16)
    __shared__ float tmpa[256];   // u-plane tmp / uv-idct results
    __shared__ float tmpb[256];   // v-plane tmp
    __shared__ float lu[64];      // downsampled u (8x8)
    __shared__ float lv[64];      // downsampled v (8x8)
    // coefficient state: [blk0..3 = y blocks][blk4 = u][blk5 = v], 6*64 floats
    __shared__ float cWx[384];
    __shared__ float cNeg[384];
    __shared__ float cBy[384];
    __shared__ float cU[384];
    __shared__ float cR[384];
    __shared__ float cWz[384];

    if (t < 64) { BBl[t] = cBB[t]; Ql[t] = cQ[t]; }

    const size_t pixbase = (((size_t)b * 512 + gy) * 512 + gx) * 3;
    const float sr = s[pixbase + 0];
    const float sg = s[pixbase + 1];
    const float sb = s[pixbase + 2];

    // ---- W: per-thread rgb -> 384 DCT coefficients in dst ----
    auto do_W = [&](float pr, float pg, float pb, float* dst) {
        __syncthreads();  // protect ly/tmpa/tmpb from previous phase's readers
        float yv = 0.299f*pr + 0.587f*pg + 0.114f*pb - 0.5f;
        float uu = -0.14714119f*pr - 0.28886916f*pg + 0.43601035f*pb;
        float vv =  0.61497538f*pr - 0.51496512f*pg - 0.10001026f*pb;
        ly[t] = yv; tmpa[t] = uu; tmpb[t] = vv;
        __syncthreads();
        if (t < 64) {                       // 2x2 average pool for chroma
            int dy = t >> 3, dx = t & 7;
            int base = dy * 32 + dx * 2;
            lu[t] = 0.25f * (tmpa[base] + tmpa[base+1] + tmpa[base+16] + tmpa[base+17]);
            lv[t] = 0.25f * (tmpb[base] + tmpb[base+1] + tmpb[base+16] + tmpb[base+17]);
        }
        __syncthreads();
        {   // y-DCT: 4 blocks x 64 coefs == 256 threads, one coef each
            int blk = t >> 6, k = t & 63, u = k >> 3, v = k & 7;
            int by = blk >> 1, bx = blk & 1;
            float bu[8], bv[8];
            #pragma unroll
            for (int i = 0; i < 8; ++i) { bu[i] = BBl[i*8+u]; bv[i] = BBl[i*8+v]; }
            const float* src = &ly[by*128 + bx*8];
            float acc = 0.f;
            #pragma unroll
            for (int i = 0; i < 8; ++i) {
                float rs = 0.f;
                #pragma unroll
                for (int j = 0; j < 8; ++j) rs = fmaf(src[i*16+j], bv[j], rs);
                acc = fmaf(rs, bu[i], acc);
            }
            dst[t] = acc;
        }
        if (t < 128) {                      // u,v DCT (one 8x8 block each)
            const float* src = (t < 64) ? lu : lv;
            int k = t & 63, u = k >> 3, v = k & 7;
            float bu[8], bv[8];
            #pragma unroll
            for (int i = 0; i < 8; ++i) { bu[i] = BBl[i*8+u]; bv[i] = BBl[i*8+v]; }
            float acc = 0.f;
            #pragma unroll
            for (int i = 0; i < 8; ++i) {
                float rs = 0.f;
                #pragma unroll
                for (int j = 0; j < 8; ++j) rs = fmaf(src[i*8+j], bv[j], rs);
                acc = fmaf(rs, bu[i], acc);
            }
            dst[256 + (t >> 6) * 64 + k] = acc;
        }
        __syncthreads();
    };

    // ---- init: Ws = W(s); negC = Q*round(Ws/Q); By = negC; u = 0; y = s ----
    do_W(sr, sg, sb, cWx);
    for (int ci = t; ci < 384; ci += 256) {
        float q = Ql[ci & 63];
        float n = q * rintf(cWx[ci] / q);
        cNeg[ci] = n;
        cBy[ci]  = n;
        cU[ci]   = 0.f;
    }
    __syncthreads();

    float yr = sr, yg = sg, yb = sb;

    #pragma unroll 1
    for (int it = 0; it < 4; ++it) {
        const float xr = yr * (1.0f/3.0f);   // xup(y) == y/3 (A == 3 exactly)
        const float xg = yg * (1.0f/3.0f);
        const float xb = yb * (1.0f/3.0f);

        do_W(xr, xg, xb, cWx);

        // ---- coefficient-domain update (elementwise) ----
        for (int ci = t; ci < 384; ci += 256) {
            float q   = Ql[ci & 63];
            float axc = -0.8f * cBy[ci] - 0.2f * cNeg[ci];   // (1-a)By - (2-a)negC
            float wx  = cWx[ci];
            float r   = -axc - wx - cU[ci];
            // QuantizationAdjustment (C = 0.5, MU = RHO = 1)
            float yq  = wx + 0.5f * r;
            float ry  = q * rintf(yq / q);
            float sgn = sgnf(r);
            float hqm = 0.5f*q - (1.0f/510.0f);
            float hqp = 0.5f*q + (1.0f/510.0f);
            float cra = 0.5f * fabsf(r);
            float c1  = -sgn * fminf(cra, fabsf(ry - yq - sgn*q*hqm));
            float sarg = yq - ry - 0.5f*r;
            float c2  = ry - hqp*q*sgnf(sarg) - yq;
            float c3  = -sgn * fminf(cra, fabsf(ry - yq - sgn*q*(1.0f + hqm)));
            auto err = [&](float d) {
                float a  = 0.5f*r + d;
                float e2 = -0.5f + q*rintf((yq + d)/q) - yq;
                return 0.5f*a*a + 0.5f*e2*e2;
            };
            float e1 = err(c1), e2 = err(c2), e3 = err(c3);
            float best = (e2 < e1) ? c2 : c1;
            float eb   = (e2 < e1) ? e2 : e1;
            float wdz  = (e3 < eb) ? c3 : best;
            cR[ci]  = r;
            cWz[ci] = wdz;
            float bynew = q * rintf((yq + wdz) / q);
            cBy[ci] = bynew;
            cU[ci]  = cU[ci] + axc + bynew;
        }
        __syncthreads();

        // ---- y = x + 0.5*Wt(r) + Wt(wdz) ----
        {   // phase 1: chroma IDCT for all four (r_u, r_v, w_u, w_v) blocks
            int sel = t >> 6, k = t & 63, i = k >> 3, j = k & 7;
            const float* src = (sel == 0) ? (cR  + 256)
                             : (sel == 1) ? (cR  + 320)
                             : (sel == 2) ? (cWz + 256)
                             :              (cWz + 320);
            float bi[8], bj[8];
            #pragma unroll
            for (int u = 0; u < 8; ++u) { bi[u] = BBl[i*8+u]; bj[u] = BBl[j*8+u]; }
            float acc = 0.f;
            #pragma unroll
            for (int u = 0; u < 8; ++u) {
                float cs = 0.f;
                #pragma unroll
                for (int v = 0; v < 8; ++v) cs = fmaf(src[u*8+v], bj[v], cs);
                acc = fmaf(cs, bi[u], acc);
            }
            tmpa[t] = acc;
        }
        __syncthreads();
        {   // phase 2: per-pixel luma IDCT (both r and wdz) + color transform
            int blk = ((py >> 3) << 1) + (px >> 3);
            int i = py & 7, j = px & 7;
            float bi[8], bj[8];
            #pragma unroll
            for (int u = 0; u < 8; ++u) { bi[u] = BBl[i*8+u]; bj[u] = BBl[j*8+u]; }
            const float* srcR = cR  + blk*64;
            const float* srcW = cWz + blk*64;
            float accR = 0.f, accW = 0.f;
            #pragma unroll
            for (int u = 0; u < 8; ++u) {
                float csR = 0.f, csW = 0.f;
                #pragma unroll
                for (int v = 0; v < 8; ++v) {
                    csR = fmaf(srcR[u*8+v], bj[v], csR);
                    csW = fmaf(srcW[u*8+v], bj[v], csW);
                }
                accR = fmaf(csR, bi[u], accR);
                accW = fmaf(csW, bi[u], accW);
            }
            int kuv = ((py >> 1) << 3) + (px >> 1);   // nearest-neighbor upsample
            float uR = clampf(tmpa[kuv],       -0.5f, 0.5f);
            float vR = clampf(tmpa[64 + kuv],  -0.5f, 0.5f);
            float uW = clampf(tmpa[128 + kuv], -0.5f, 0.5f);
            float vW = clampf(tmpa[192 + kuv], -0.5f, 0.5f);
            float yR = clampf(accR + 0.5f, 0.f, 1.f);
            float yW = clampf(accW + 0.5f, 0.f, 1.f);
            float rR = clampf(yR + 1.13988303f*vR, 0.f, 1.f);
            float gR = clampf(yR - 0.394642334f*uR - 0.58062185f*vR, 0.f, 1.f);
            float bR = clampf(yR + 2.03206185f*uR, 0.f, 1.f);
            float rW = clampf(yW + 1.13988303f*vW, 0.f, 1.f);
            float gW = clampf(yW - 0.394642334f*uW - 0.58062185f*vW, 0.f, 1.f);
            float bW = clampf(yW + 2.03206185f*uW, 0.f, 1.f);
            yr = xr + 0.5f*rR + rW;
            yg = xg + 0.5f*gR + gW;
            yb = xb + 0.5f*bR + bW;
        }
        // next do_W starts with a __syncthreads(), protecting cR/cWz/tmpa reads
    }

    // final xup(y) == y/3
    out[pixbase + 0] = yr * (1.0f/3.0f);
    out[pixbase + 1] = yg * (1.0f/3.0f);
    out[pixbase + 2] = yb * (1.0f/3.0f);
}

extern "C" void kernel_launch(void* const* d_in, const int* in_sizes, int n_in,
                              void* d_out, int out_size, void* d_ws, size_t ws_size,
                              hipStream_t stream) {
    const float* s = (const float*)d_in[0];
    float* out = (float*)d_out;
    smooth_jpeg_kernel<<<dim3(4096), dim3(256), 0, stream>>>(s, out);
}

// Round 3
// 49.134 us; speedup vs baseline: 1.8870x; 1.8870x over previous
//
#include <hip/hip_runtime.h>
#include <math.h>

// ---- DCT basis with the 0.25 global scale folded symmetrically (BB = 0.5*B1)
// so  F[i,j,u*8+v] = BB[i][u]*BB[j][v]  works for BOTH forward and inverse.
#define H1 0.49039264020161522f
#define H2 0.46193976625564338f
#define H3 0.41573480615127262f
#define H4 0.35355339059327376f
#define H5 0.27778511650980111f
#define H6 0.19134171618254489f
#define H7 0.09754516100806413f

__device__ __constant__ float cBB[64] = {
  H4,  H1,  H2,  H3,  H4,  H5,  H6,  H7,
  H4,  H3,  H6, -H7, -H4, -H1, -H2, -H5,
  H4,  H5, -H6, -H1, -H4,  H7,  H2,  H3,
  H4,  H7, -H2, -H5,  H4,  H3, -H6, -H1,
  H4, -H7, -H2,  H5,  H4, -H3, -H6,  H1,
  H4, -H5, -H6,  H1, -H4, -H7,  H2, -H3,
  H4, -H3,  H6,  H7, -H4,  H1, -H2,  H5,
  H4, -H1,  H2, -H3,  H4, -H5,  H6, -H7,
};

__device__ __constant__ float cQ[64] = {
  16.f/255.f, 11.f/255.f, 10.f/255.f, 16.f/255.f, 24.f/255.f, 40.f/255.f, 51.f/255.f, 61.f/255.f,
  12.f/255.f, 12.f/255.f, 14.f/255.f, 19.f/255.f, 26.f/255.f, 58.f/255.f, 60.f/255.f, 55.f/255.f,
  14.f/255.f, 13.f/255.f, 16.f/255.f, 24.f/255.f, 40.f/255.f, 57.f/255.f, 69.f/255.f, 56.f/255.f,
  14.f/255.f, 17.f/255.f, 22.f/255.f, 29.f/255.f, 51.f/255.f, 87.f/255.f, 80.f/255.f, 62.f/255.f,
  18.f/255.f, 22.f/255.f, 37.f/255.f, 56.f/255.f, 68.f/255.f, 109.f/255.f, 103.f/255.f, 77.f/255.f,
  24.f/255.f, 35.f/255.f, 55.f/255.f, 64.f/255.f, 81.f/255.f, 104.f/255.f, 113.f/255.f, 92.f/255.f,
  49.f/255.f, 64.f/255.f, 78.f/255.f, 87.f/255.f, 103.f/255.f, 121.f/255.f, 120.f/255.f, 101.f/255.f,
  72.f/255.f, 92.f/255.f, 95.f/255.f, 98.f/255.f, 112.f/255.f, 100.f/255.f, 103.f/255.f, 99.f/255.f,
};

__device__ __forceinline__ float clampf(float x, float lo, float hi) {
    return fminf(fmaxf(x, lo), hi);
}
__device__ __forceinline__ float sgnf(float x) {
    return (x > 0.f) ? 1.f : ((x < 0.f) ? -1.f : 0.f);
}

__global__ __launch_bounds__(256)
void smooth_jpeg_kernel(const float* __restrict__ s, float* __restrict__ out)
{
    const int t    = threadIdx.x;
    const int py   = t >> 4, px = t & 15;
    const int tile = blockIdx.x;          // 4 * 32 * 32 tiles
    const int b    = tile >> 10;
    const int ti   = tile & 1023;
    const int gy   = (ti >> 5) * 16 + py;
    const int gx   = (ti & 31) * 16 + px;

    __shared__ float BBl[64];
    __shared__ float Ql[64];
    __shared__ float ly[256];     // luma plane / chroma-IDCT pass1 intermediate
    __shared__ float tmpa[256];   // y row-DCT intermediate / final chroma pixels
    __shared__ float tmpb[256];   // chroma row-DCT intermediate / lumaW IDCT pass1
    __shared__ float tmpc[256];   // lumaR IDCT pass1 intermediate
    __shared__ float lu[64];      // pooled u (8x8)
    __shared__ float lv[64];      // pooled v (8x8)
    __shared__ float cR[384];     // r coefficients   [4 y blocks][u][v]
    __shared__ float cWz[384];    // wdz coefficients

    if (t < 64) { BBl[t] = cBB[t]; Ql[t] = cQ[t]; }

    const size_t pixbase = (((size_t)b * 512 + gy) * 512 + gx) * 3;
    const float sr = s[pixbase + 0];
    const float sg = s[pixbase + 1];
    const float sb = s[pixbase + 2];

    const int kY   = t & 63;         // packed (u,v) / (i,j)
    const int blkY = t >> 6;         // block / selector id
    const int byB  = blkY >> 1, bxB = blkY & 1;

    // per-thread coefficient-domain state (thread t owns coef t, and 256+t if t<128)
    float negY = 0.f, byY = 0.f, uY = 0.f;
    float negC2 = 0.f, byC2 = 0.f, uC2 = 0.f;

    // ---- Phase A: color transform + in-register 2x2 chroma pool ----
    auto phaseA = [&](float pr, float pg, float pb) {
        __syncthreads();
        float yv = 0.299f*pr + 0.587f*pg + 0.114f*pb - 0.5f;
        float uu = -0.14714119f*pr - 0.28886916f*pg + 0.43601035f*pb;
        float vv =  0.61497538f*pr - 0.51496512f*pg - 0.10001026f*pb;
        ly[t] = yv;
        float ub = __shfl_xor(uu, 1),  uc = __shfl_xor(uu, 16), ud = __shfl_xor(uu, 17);
        float vb = __shfl_xor(vv, 1),  vc = __shfl_xor(vv, 16), vd = __shfl_xor(vv, 17);
        if ((t & 17) == 0) {          // py even, px even
            int ci = ((py >> 1) << 3) + (px >> 1);
            lu[ci] = 0.25f * (((uu + ub) + uc) + ud);   // same order as a+b+c+d
            lv[ci] = 0.25f * (((vv + vb) + vc) + vd);
        }
    };

    // ---- Phase C: row DCT (inner j-sum) -> tmpa (y, [row][bx*8+v]), tmpb (chroma) ----
    auto phaseC = [&]() {
        __syncthreads();
        int v = t & 7;
        float bv[8];
        #pragma unroll
        for (int j = 0; j < 8; ++j) bv[j] = BBl[j*8 + v];
        {
            int rowi = t >> 4, bx = (t >> 3) & 1;
            const float* src = &ly[rowi*16 + bx*8];
            float acc = 0.f;
            #pragma unroll
            for (int j = 0; j < 8; ++j) acc = fmaf(src[j], bv[j], acc);
            tmpa[t] = acc;     // index = rowi*16 + bx*8 + v == t
        }
        if (t < 128) {
            int p = t >> 6, r8 = (t >> 3) & 7;
            const float* src = (p ? lv : lu) + r8*8;
            float acc = 0.f;
            #pragma unroll
            for (int j = 0; j < 8; ++j) acc = fmaf(src[j], bv[j], acc);
            tmpb[t] = acc;     // index = p*64 + r8*8 + v == t
        }
    };

    // ---- Phase D1: column DCT (outer i-sum) -> per-thread coefficients ----
    auto colDCT = [&](float& wy, float& wc) {
        __syncthreads();
        int u = kY >> 3, v = kY & 7;
        float bu[8];
        #pragma unroll
        for (int i = 0; i < 8; ++i) bu[i] = BBl[i*8 + u];
        float acc = 0.f;
        #pragma unroll
        for (int i = 0; i < 8; ++i)
            acc = fmaf(tmpa[(byB*8 + i)*16 + bxB*8 + v], bu[i], acc);
        wy = acc;
        if (t < 128) {
            float accc = 0.f;
            #pragma unroll
            for (int i = 0; i < 8; ++i)
                accc = fmaf(tmpb[(t & 64) + i*8 + v], bu[i], accc);
            wc = accc;
        }
    };

    // ---- Quantization adjustment (register-local; 3 divides per coef) ----
    auto quant = [&](float wx, float neg, float& by, float& uu, int idx) {
        float q    = Ql[idx & 63];
        float axc  = -0.8f*by - 0.2f*neg;          // (1-a)By - (2-a)negC
        float r    = -axc - wx - uu;
        float yq   = wx + 0.5f*r;
        float r0   = rintf(yq / q);
        float ry   = q * r0;
        float sgn  = sgnf(r);
        float hqm  = 0.5f*q - (1.0f/510.0f);
        float hqp  = 0.5f*q + (1.0f/510.0f);
        float aa   = 0.5f*fabsf(r);
        float b1   = fabsf(ry - yq - sgn*q*hqm);
        float b3   = fabsf(ry - yq - sgn*q*(1.0f + hqm));
        float c1   = -sgn * fminf(aa, b1);
        float c3   = -sgn * fminf(aa, b3);
        float sarg = yq - ry - 0.5f*r;
        float sg2  = sgnf(sarg);
        float c2   = ry - hqp*q*sg2 - yq;
        // rounds: c1/c3 generic (real divide). c2's offset from ry is
        // hqp*q with hqp = q/2 + 1/510 <= 0.24 quantization-units for every
        // table entry (max q = 121/255 -> hqp = 0.239), i.e. strictly inside
        // the rounding cell of r0 with >=0.26-unit margin vs ~1e-6 fp noise:
        //   rint((yq + c2)/q) == r0 exactly.  (Round-2 bug: used r0 - sg2.)
        float rint1 = rintf((yq + c1) / q);
        float rint3 = rintf((yq + c3) / q);
        float rint2 = r0;
        float a1 = 0.5f*r + c1;
        float a2 = 0.5f*r + c2;
        float a3 = 0.5f*r + c3;
        float e1 = (-0.5f + q*rint1) - yq;
        float e2 = (-0.5f + q*rint2) - yq;
        float e3 = (-0.5f + q*rint3) - yq;
        float err1 = 0.5f*a1*a1 + 0.5f*e1*e1;
        float err2 = 0.5f*a2*a2 + 0.5f*e2*e2;
        float err3 = 0.5f*a3*a3 + 0.5f*e3*e3;
        bool p2 = err2 < err1;
        float best = p2 ? c2 : c1;
        float ebst = p2 ? err2 : err1;
        float rbst = p2 ? rint2 : rint1;
        bool p3 = err3 < ebst;
        float wdz  = p3 ? c3 : best;
        float rwin = p3 ? rint3 : rbst;     // == rint((yq+wdz)/q) bit-exactly
        cR[idx]  = r;
        cWz[idx] = wdz;
        by = q * rwin;
        uu = (uu + axc) + by;
    };

    // ---- Phase E: IDCT pass1 (inner v-sum) for chroma + both luma transforms ----
    auto phaseE = [&]() {
        __syncthreads();
        int u = kY >> 3, j = kY & 7;
        float bj[8];
        #pragma unroll
        for (int v = 0; v < 8; ++v) bj[v] = BBl[j*8 + v];
        const float* csrc = ((blkY < 2) ? cR : cWz) + 256 + (blkY & 1)*64 + u*8;
        float acc = 0.f;
        #pragma unroll
        for (int v = 0; v < 8; ++v) acc = fmaf(csrc[v], bj[v], acc);
        ly[t] = acc;                               // chroma intermediate [sel][u][j]
        const float* r_src = cR  + blkY*64 + u*8;
        const float* w_src = cWz + blkY*64 + u*8;
        float aR = 0.f, aW = 0.f;
        #pragma unroll
        for (int v = 0; v < 8; ++v) {
            aR = fmaf(r_src[v], bj[v], aR);
            aW = fmaf(w_src[v], bj[v], aW);
        }
        tmpc[t] = aR;                              // lumaR intermediate [blk][u][j]
        tmpb[t] = aW;                              // lumaW intermediate [blk][u][j]
    };

    // ---- Phase F: chroma IDCT pass2 (outer u-sum) -> chroma pixels in tmpa ----
    auto phaseF = [&]() {
        __syncthreads();
        int i = kY >> 3, j = kY & 7;
        float bi[8];
        #pragma unroll
        for (int u = 0; u < 8; ++u) bi[u] = BBl[i*8 + u];
        float acc = 0.f;
        #pragma unroll
        for (int u = 0; u < 8; ++u) acc = fmaf(ly[blkY*64 + u*8 + j], bi[u], acc);
        tmpa[t] = acc;                             // [sel][i][j]
    };

    // ---- init: Ws = W(s); negC = Q*round(Ws/Q); By = negC; u = 0; y = s ----
    phaseA(sr, sg, sb);
    phaseC();
    {
        float wy = 0.f, wc = 0.f;
        colDCT(wy, wc);
        float q = Ql[kY];
        negY = q * rintf(wy / q); byY = negY; uY = 0.f;
        if (t < 128) { negC2 = q * rintf(wc / q); byC2 = negC2; uC2 = 0.f; }
    }

    float yr = sr, yg = sg, yb = sb;

    #pragma unroll 1
    for (int it = 0; it < 4; ++it) {
        const float xr = yr * (1.0f/3.0f);   // xup(y) == y/3 (A == 3 exactly)
        const float xg = yg * (1.0f/3.0f);
        const float xb = yb * (1.0f/3.0f);

        phaseA(xr, xg, xb);
        phaseC();
        float wy = 0.f, wc = 0.f;
        colDCT(wy, wc);
        quant(wy, negY, byY, uY, t);
        if (t < 128) quant(wc, negC2, byC2, uC2, 256 + t);
        phaseE();
        phaseF();

        // ---- Phase G: luma IDCT pass2 + upsample + color, all per-pixel ----
        __syncthreads();
        {
            int blk = ((py >> 3) << 1) + (px >> 3);
            int i = py & 7, j = px & 7;
            float bi[8];
            #pragma unroll
            for (int u = 0; u < 8; ++u) bi[u] = BBl[i*8 + u];
            float accR = 0.f, accW = 0.f;
            #pragma unroll
            for (int u = 0; u < 8; ++u) {
                accR = fmaf(tmpc[blk*64 + u*8 + j], bi[u], accR);
                accW = fmaf(tmpb[blk*64 + u*8 + j], bi[u], accW);
            }
            int kuv = ((py >> 1) << 3) + (px >> 1);   // nearest-neighbor upsample
            float uR = clampf(tmpa[kuv],       -0.5f, 0.5f);
            float vR = clampf(tmpa[64 + kuv],  -0.5f, 0.5f);
            float uW = clampf(tmpa[128 + kuv], -0.5f, 0.5f);
            float vW = clampf(tmpa[192 + kuv], -0.5f, 0.5f);
            float yR = clampf(accR + 0.5f, 0.f, 1.f);
            float yW = clampf(accW + 0.5f, 0.f, 1.f);
            float rR = clampf(yR + 1.13988303f*vR, 0.f, 1.f);
            float gR = clampf(yR - 0.394642334f*uR - 0.58062185f*vR, 0.f, 1.f);
            float bR = clampf(yR + 2.03206185f*uR, 0.f, 1.f);
            float rW = clampf(yW + 1.13988303f*vW, 0.f, 1.f);
            float gW = clampf(yW - 0.394642334f*uW - 0.58062185f*vW, 0.f, 1.f);
            float bW = clampf(yW + 2.03206185f*uW, 0.f, 1.f);
            yr = xr + 0.5f*rR + rW;
            yg = xg + 0.5f*gR + gW;
            yb = xb + 0.5f*bR + bW;
        }
    }

    // final xup(y) == y/3
    out[pixbase + 0] = yr * (1.0f/3.0f);
    out[pixbase + 1] = yg * (1.0f/3.0f);
    out[pixbase + 2] = yb * (1.0f/3.0f);
}

extern "C" void kernel_launch(void* const* d_in, const int* in_sizes, int n_in,
                              void* d_out, int out_size, void* d_ws, size_t ws_size,
                              hipStream_t stream) {
    const float* s = (const float*)d_in[0];
    float* out = (float*)d_out;
    smooth_jpeg_kernel<<<dim3(4096), dim3(256), 0, stream>>>(s, out);
}